// Round 1
// baseline (553.309 us; speedup 1.0000x reference)
//
#include <hip/hip_runtime.h>

// AlignmentMatrix: out[b,i,j] = sum_d body[b,i,d]*w3[d]*pun[b,j,d]
//                             + dot(body[b,i,:],w1) + dot(pun[b,j,:],w2)
// B=64, L=1024, D=128, fp32 in/out.
//
// Round 1 baseline: fp32 vector-ALU batched GEMM, 64x64 tile/block,
// K=128 fully LDS-resident (no K loop), XOR-swizzled LDS for b128 reads,
// rank-1 terms fused via in-block shuffle reduction.

#define LSEQ 1024
#define H2K  128

__global__ __launch_bounds__(256) void align_kernel(
    const float* __restrict__ body, const float* __restrict__ pun,
    const float* __restrict__ w_u, float* __restrict__ out)
{
    // 64 rows x 32 float4-groups each = 32 KB per tile; total 64 KB static LDS.
    __shared__ float4 As4[64 * 32];   // body_tile * w3, swizzled
    __shared__ float4 Bs4[64 * 32];   // pun_tile, swizzled

    const int bb     = blockIdx.z;
    const int tile_i = blockIdx.y * 64;
    const int tile_j = blockIdx.x * 64;
    const int tx = threadIdx.x, ty = threadIdx.y;   // 16 x 16
    const int t  = ty * 16 + tx;
    const int r  = t >> 2;        // 0..63: tile row (A) / tile col (B) this thread stages
    const int c4 = t & 3;         // 4 threads per row, 64B contiguous global reads

    const float4* Arow = (const float4*)(body + ((size_t)bb * LSEQ + tile_i + r) * H2K);
    const float4* Brow = (const float4*)(pun  + ((size_t)bb * LSEQ + tile_j + r) * H2K);
    const float4* w1v  = (const float4*)(w_u);
    const float4* w2v  = (const float4*)(w_u + H2K);
    const float4* w3v  = (const float4*)(w_u + 2 * H2K);
    const int sw = (r >> 2) & 7;  // XOR swizzle key (16B-group granularity)

    // Stage tiles + accumulate partial rank-1 dots (8 groups x 4 floats = 32 k's each).
    float pA = 0.f, pB = 0.f;
#pragma unroll
    for (int l = 0; l < 8; ++l) {
        int g = c4 + l * 4;                 // group 0..31 (k = 4*g)
        float4 av = Arow[g];
        float4 bv = Brow[g];
        float4 w1 = w1v[g], w2 = w2v[g], w3 = w3v[g];
        pA += av.x * w1.x + av.y * w1.y + av.z * w1.z + av.w * w1.w;
        pB += bv.x * w2.x + bv.y * w2.y + bv.z * w2.z + bv.w * w2.w;
        av.x *= w3.x; av.y *= w3.y; av.z *= w3.z; av.w *= w3.w;
        As4[r * 32 + (g ^ sw)] = av;
        Bs4[r * 32 + (g ^ sw)] = bv;
    }
    // Reduce the 4 lanes covering one row (lanes r*4+0..3, contiguous in-wave).
    pA += __shfl_xor(pA, 1); pA += __shfl_xor(pA, 2);
    pB += __shfl_xor(pB, 1); pB += __shfl_xor(pB, 2);
    __syncthreads();

    // 4x4 micro-tile per thread; rows ty*4+s, cols tx*4+c.
    float acc[4][4] = {};
    const int swa = ty & 7;   // == ((ty*4+s)>>2)&7, matches writer swizzle
    const int swb = tx & 7;
#pragma unroll 4
    for (int g = 0; g < 32; ++g) {
        float4 a[4], b[4];
        const int ga = g ^ swa, gb = g ^ swb;
#pragma unroll
        for (int s = 0; s < 4; ++s) a[s] = As4[(ty * 4 + s) * 32 + ga];
#pragma unroll
        for (int c = 0; c < 4; ++c) b[c] = Bs4[(tx * 4 + c) * 32 + gb];
#pragma unroll
        for (int i = 0; i < 4; ++i)
#pragma unroll
            for (int j = 0; j < 4; ++j)
                acc[i][j] += a[i].x * b[j].x + a[i].y * b[j].y
                           + a[i].z * b[j].z + a[i].w * b[j].w;
    }

    // Park rank-1 terms in LDS (reuse As4 region; all As4/Bs4 reads are done).
    __syncthreads();
    float* sAB = (float*)As4;             // [0..63]=s_body(tile rows), [64..127]=s_pun(tile cols)
    if (c4 == 0) { sAB[r] = pA; sAB[64 + r] = pB; }
    __syncthreads();

    float spv[4];
#pragma unroll
    for (int j = 0; j < 4; ++j) spv[j] = sAB[64 + tx * 4 + j];
#pragma unroll
    for (int i = 0; i < 4; ++i) {
        const int row = tile_i + ty * 4 + i;
        const float sb = sAB[ty * 4 + i];
        float4 o;
        o.x = acc[i][0] + sb + spv[0];
        o.y = acc[i][1] + sb + spv[1];
        o.z = acc[i][2] + sb + spv[2];
        o.w = acc[i][3] + sb + spv[3];
        *(float4*)(out + ((size_t)bb * LSEQ + row) * LSEQ + tile_j + tx * 4) = o;
    }
}

extern "C" void kernel_launch(void* const* d_in, const int* in_sizes, int n_in,
                              void* d_out, int out_size, void* d_ws, size_t ws_size,
                              hipStream_t stream) {
    // d_in: [0]=batch_size (scalar), [1]=body (B*1024*128 f32),
    //       [2]=pun (B*1024*128 f32), [3]=w_u (384 f32)
    const float* body = (const float*)d_in[1];
    const float* pun  = (const float*)d_in[2];
    const float* w_u  = (const float*)d_in[3];
    float* out = (float*)d_out;
    const int B = in_sizes[1] / (LSEQ * H2K);
    dim3 grid(LSEQ / 64, LSEQ / 64, B);
    dim3 block(16, 16, 1);
    align_kernel<<<grid, block, 0, stream>>>(body, pun, w_u, out);
}

// Round 2
// 374.568 us; speedup vs baseline: 1.4772x; 1.4772x over previous
//
#include <hip/hip_runtime.h>

// AlignmentMatrix: out[b,i,j] = sum_d body[b,i,d]*w3[d]*pun[b,j,d]
//                             + dot(body[b,i,:],w1) + dot(pun[b,j,:],w2)
// B=64, L=1024, D=128, fp32 in/out.
//
// R2: split-bf16 MFMA (a=a_hi+a_lo; 3 MFMA products ~ fp32 precision).
// 128x128 tile / 512 threads, K chunked 4x32, LDS in fragment order
// (conflict-free b128 reads+writes). Rank-1 terms precomputed into d_ws.

#define LSEQ 1024
#define H2K  128

typedef __attribute__((ext_vector_type(8))) short bfrag;
typedef __attribute__((ext_vector_type(4))) float f32x4;

__device__ __forceinline__ short f2bf(float x) {
    unsigned u = __float_as_uint(x);
    unsigned r = (u + 0x7fff + ((u >> 16) & 1)) >> 16;   // RNE
    return (short)r;
}
__device__ __forceinline__ float bf2f(short s) {
    return __uint_as_float(((unsigned)(unsigned short)s) << 16);
}

// --- pre-kernel: s_body = body.w1, s_pun = pun.w2  -> ws[0:65536], ws[65536:131072]
__global__ __launch_bounds__(256) void rank1_kernel(
    const float* __restrict__ body, const float* __restrict__ pun,
    const float* __restrict__ w_u, float* __restrict__ ws)
{
    const int flag = blockIdx.y;                       // 0=body/w1, 1=pun/w2
    const float* src = flag ? pun : body;
    const float4* wv = (const float4*)(w_u + flag * H2K);
    float* dst = ws + (size_t)flag * 65536;
    const int t = threadIdx.x;
    const int c4 = t & 3;
    const size_t row = (size_t)blockIdx.x * 64 + (t >> 2);
    const float4* rowp = (const float4*)(src + row * H2K);
    float p = 0.f;
#pragma unroll
    for (int l = 0; l < 8; ++l) {
        int g = c4 + l * 4;
        float4 v = rowp[g], w = wv[g];
        p += v.x * w.x + v.y * w.y + v.z * w.z + v.w * w.w;
    }
    p += __shfl_xor(p, 1);
    p += __shfl_xor(p, 2);
    if (c4 == 0) dst[row] = p;
}

// --- main kernel
__global__ __launch_bounds__(512, 2) void align_mfma(
    const float* __restrict__ body, const float* __restrict__ pun,
    const float* __restrict__ w_u, const float* __restrict__ ws,
    float* __restrict__ out)
{
    // One K-chunk (128 rows x 32 k) per operand, hi+lo bf16, fragment order.
    __shared__ short Ah[4096], Al[4096], Bh[4096], Bl[4096];   // 8 KB each = 32 KB

    const int bb = blockIdx.z;
    const int ti = blockIdx.y * 128, tj = blockIdx.x * 128;
    const int t    = threadIdx.x;
    const int lane = t & 63;
    const int w    = t >> 6;                // wave id 0..7

    // Staging: thread t owns fragment (mt = w, lane) of the chunk:
    //   row  = w*16 + (lane&15), k8 = lane>>4 (8 consecutive k's)
    const int srow = w * 16 + (lane & 15);
    const int k8   = lane >> 4;
    const float4* a4  = (const float4*)(body + ((size_t)bb * LSEQ + ti + srow) * H2K) + k8 * 2;
    const float4* b4  = (const float4*)(pun  + ((size_t)bb * LSEQ + tj + srow) * H2K) + k8 * 2;
    const float4* w34 = (const float4*)(w_u + 2 * H2K) + k8 * 2;

    // Compute: wave covers mt in {mt0,mt0+1}, nt in {nt0..nt0+3}
    const int mt0 = (w >> 1) * 2;
    const int nt0 = (w & 1) * 4;
    f32x4 acc[2][4] = {};

    for (int kt = 0; kt < 4; ++kt) {
        if (kt) __syncthreads();           // LDS reuse guard

        // ---- stage chunk kt ----
        float4 xa0 = a4[kt * 8], xa1 = a4[kt * 8 + 1];
        float4 xb0 = b4[kt * 8], xb1 = b4[kt * 8 + 1];
        float4 w0  = w34[kt * 8], w1 = w34[kt * 8 + 1];
        float va[8] = { xa0.x * w0.x, xa0.y * w0.y, xa0.z * w0.z, xa0.w * w0.w,
                        xa1.x * w1.x, xa1.y * w1.y, xa1.z * w1.z, xa1.w * w1.w };
        float vb[8] = { xb0.x, xb0.y, xb0.z, xb0.w, xb1.x, xb1.y, xb1.z, xb1.w };
        bfrag ahf, alf, bhf, blf;
#pragma unroll
        for (int e = 0; e < 8; ++e) {
            short h = f2bf(va[e]);
            ahf[e] = h;
            alf[e] = f2bf(va[e] - bf2f(h));
            h = f2bf(vb[e]);
            bhf[e] = h;
            blf[e] = f2bf(vb[e] - bf2f(h));
        }
        *(bfrag*)&Ah[t * 8] = ahf;
        *(bfrag*)&Al[t * 8] = alf;
        *(bfrag*)&Bh[t * 8] = bhf;
        *(bfrag*)&Bl[t * 8] = blf;
        __syncthreads();

        // ---- compute chunk kt: 24 MFMAs ----
        bfrag ah[2], al[2], bh[4], bl[4];
#pragma unroll
        for (int i = 0; i < 2; ++i) {
            ah[i] = *(const bfrag*)&Ah[((mt0 + i) * 64 + lane) * 8];
            al[i] = *(const bfrag*)&Al[((mt0 + i) * 64 + lane) * 8];
        }
#pragma unroll
        for (int j = 0; j < 4; ++j) {
            bh[j] = *(const bfrag*)&Bh[((nt0 + j) * 64 + lane) * 8];
            bl[j] = *(const bfrag*)&Bl[((nt0 + j) * 64 + lane) * 8];
        }
#pragma unroll
        for (int i = 0; i < 2; ++i)
#pragma unroll
            for (int j = 0; j < 4; ++j) {
                acc[i][j] = __builtin_amdgcn_mfma_f32_16x16x32_bf16(ah[i], bh[j], acc[i][j], 0, 0, 0);
                acc[i][j] = __builtin_amdgcn_mfma_f32_16x16x32_bf16(ah[i], bl[j], acc[i][j], 0, 0, 0);
                acc[i][j] = __builtin_amdgcn_mfma_f32_16x16x32_bf16(al[i], bh[j], acc[i][j], 0, 0, 0);
            }
    }

    // ---- epilogue: + s_body[i] + s_pun[j], store ----
    const float* sbp = ws + (size_t)bb * LSEQ;            // index by local i
    const float* spp = ws + 65536 + (size_t)bb * LSEQ;    // index by local j
    const int quad = lane >> 4, ln = lane & 15;
#pragma unroll
    for (int i = 0; i < 2; ++i) {
        const int rbase = ti + (mt0 + i) * 16 + quad * 4;  // local row of reg 0
#pragma unroll
        for (int j = 0; j < 4; ++j) {
            const int col = tj + (nt0 + j) * 16 + ln;
            const float spv = spp[col];
#pragma unroll
            for (int v = 0; v < 4; ++v) {
                const int row = rbase + v;
                out[((size_t)bb * LSEQ + row) * LSEQ + col] = acc[i][j][v] + sbp[row] + spv;
            }
        }
    }
}

extern "C" void kernel_launch(void* const* d_in, const int* in_sizes, int n_in,
                              void* d_out, int out_size, void* d_ws, size_t ws_size,
                              hipStream_t stream) {
    const float* body = (const float*)d_in[1];
    const float* pun  = (const float*)d_in[2];
    const float* w_u  = (const float*)d_in[3];
    float* out = (float*)d_out;
    float* ws  = (float*)d_ws;
    const int B = in_sizes[1] / (LSEQ * H2K);

    dim3 g1((B * LSEQ) / 64, 2, 1);
    rank1_kernel<<<g1, 256, 0, stream>>>(body, pun, w_u, ws);

    dim3 g2(LSEQ / 128, LSEQ / 128, B);
    align_mfma<<<g2, 512, 0, stream>>>(body, pun, w_u, ws, out);
}